// Round 1
// baseline (1066.404 us; speedup 1.0000x reference)
//
#include <hip/hip_runtime.h>

#define B_ 8192
#define T_ 36
#define F_ 36
#define N_ELEM (B_*T_*F_)   // 10616832

typedef __attribute__((ext_vector_type(8))) short bf16x8;
typedef __attribute__((ext_vector_type(4))) float f32x4;

__device__ inline short f2bf(float x){
  union { float f; unsigned u; } v; v.f = x;
  unsigned r = v.u + 0x7FFFu + ((v.u >> 16) & 1u);
  return (short)(r >> 16);
}
__device__ inline float sigm(float x){ return 1.f/(1.f+__expf(-x)); }
__device__ inline float tanhc(float x){
  x = fminf(fmaxf(x, -15.f), 15.f);
  float e = __expf(-2.f*x);
  return (1.f - e)/(1.f + e);
}

// ws layout (bytes)
#define WS_WC   0         // bf16 [512][256]: cols 0..107=W_ih, 108..127=0, 128..255=W_hh
#define WS_WH   262144    // bf16 [2][48][128]: W_hist split per direction, rows 36..47 = 0
#define WS_WP   286720    // bf16 [48][128]:   W_wc padded (k 72..127 = 0)
#define WS_BIAS 299008    // f32 [512]: b_ih + b_hh
#define WS_LACC 301056    // f32 [72][16]: num[t] at [t][0], den[t] at [36+t][0]

__global__ __launch_bounds__(256) void prep_kernel(
    const float* __restrict__ Wih, const float* __restrict__ Whh,
    const float* __restrict__ bih, const float* __restrict__ bhh,
    const float* __restrict__ Whist, const float* __restrict__ Wwc,
    char* __restrict__ ws)
{
  short* Wc   = (short*)(ws + WS_WC);
  short* Wh   = (short*)(ws + WS_WH);
  short* Wp   = (short*)(ws + WS_WP);
  float* bias = (float*)(ws + WS_BIAS);
  float* lacc = (float*)(ws + WS_LACC);
  int i = blockIdx.x*256 + threadIdx.x;
  if (i < 131072){
    int n = i >> 8, k = i & 255;
    float v = 0.f;
    if (k < 108) v = Wih[n*108 + k];
    else if (k >= 128) v = Whh[n*128 + (k - 128)];
    Wc[i] = f2bf(v);
  }
  if (i < 12288){
    int d = i / 6144, rem = i % 6144, f = rem >> 7, k = rem & 127;
    Wh[i] = (f < 36) ? f2bf(Whist[f*256 + d*128 + k]) : (short)0;
  }
  if (i < 6144){
    int f = i >> 7, k = i & 127;
    Wp[i] = (f < 36 && k < 72) ? f2bf(Wwc[f*72 + k]) : (short)0;
  }
  if (i < 512) bias[i] = bih[i] + bhh[i];
  if (i < 1152) lacc[i] = 0.f;
}

// Persistent LSTM: one block = 64 batch rows x one direction. 8 waves.
// LDS u[64][256] bf16, XOR-swizzled (byte ^= (row&7)<<4): k 0..107 = x_t, 108..127 = 0, 128..255 = h.
// Wave w owns gate columns j in [w*16, w*16+16): gate N-tiles {w, w+8, w+16, w+24}.
__global__ __launch_bounds__(512, 1) void lstm_kernel(
  const float* __restrict__ fv, const float* __restrict__ fm, const float* __restrict__ fd,
  const float* __restrict__ bv, const float* __restrict__ bm, const float* __restrict__ bd,
  const char* __restrict__ ws, float* __restrict__ out)
{
  int dir = blockIdx.x & 1, tile = blockIdx.x >> 1;
  int b0 = tile * 64;
  const float* V = dir ? bv : fv;
  const float* M = dir ? bm : fm;
  const float* D = dir ? bd : fd;
  const short* Wc   = (const short*)(ws + WS_WC);
  const short* Wh   = (const short*)(ws + WS_WH) + dir*6144;
  const float* bias = (const float*)(ws + WS_BIAS);
  float* imp = out + 1;

  __shared__ short u[64*256];
  int tid = threadIdx.x, w = tid >> 6, l = tid & 63;
  int lr = l & 15, lg = l >> 4;
  int jw = w * 16, j = jw + lr;

  for (int i = tid; i < 64*256; i += 512) u[i] = 0;

  float c[4][4];
  #pragma unroll
  for (int a = 0; a < 4; ++a)
    #pragma unroll
    for (int b = 0; b < 4; ++b) c[a][b] = 0.f;

  float bi = bias[j], bff = bias[128 + j], bg = bias[256 + j], bo = bias[384 + j];

  for (int t = 0; t < 36; ++t) {
    // stage x_t = [values | masks | deltas] as bf16 into LDS (swizzled)
    for (int idx = tid; idx < 1728; idx += 512) {
      int a = idx / 576, rem = idx - a*576;
      int r = rem / 9, q = rem - r*9;
      const float* src = (a == 0) ? V : (a == 1) ? M : D;
      float4 x4 = *(const float4*)(src + (b0 + r)*1296 + t*36 + q*4);
      int k = a*36 + q*4;
      int off = ((r << 9) + (k << 1)) ^ ((r & 7) << 4);
      short4 s4 = { f2bf(x4.x), f2bf(x4.y), f2bf(x4.z), f2bf(x4.w) };
      *(short4*)((char*)u + off) = s4;
    }
    __syncthreads();

    // emit pre-update hidden: xh = h @ W_hist_dir^T, atomically accumulate into imputations
    if (t > 0) {
      int mt  = w >> 1;
      int tout = dir ? (35 - t) : t;
      int ntb = (w & 1) ? 2 : 0;
      int ntn = (w & 1) ? 1 : 2;
      f32x4 ea[2] = {{0.f,0.f,0.f,0.f},{0.f,0.f,0.f,0.f}};
      #pragma unroll
      for (int kc = 0; kc < 4; ++kc) {
        int r = mt*16 + lr, k = 128 + kc*32 + lg*8;
        bf16x8 af = *(bf16x8*)((char*)u + (((r << 9) + (k << 1)) ^ ((r & 7) << 4)));
        #pragma unroll
        for (int n = 0; n < 2; ++n) if (n < ntn) {
          int f = (ntb + n)*16 + lr;
          bf16x8 bfr = *(const bf16x8*)(Wh + f*128 + kc*32 + lg*8);
          ea[n] = __builtin_amdgcn_mfma_f32_16x16x32_bf16(af, bfr, ea[n], 0, 0, 0);
        }
      }
      #pragma unroll
      for (int n = 0; n < 2; ++n) if (n < ntn) {
        int f = (ntb + n)*16 + lr;
        if (f < 36) {
          #pragma unroll
          for (int reg = 0; reg < 4; ++reg) {
            int rr = mt*16 + lg*4 + reg;
            atomicAdd(imp + ((b0 + rr)*36 + tout)*36 + f, ea[n][reg]);
          }
        }
      }
    }

    if (t == 35) break;

    // gates = u @ Wc^T : K = 256 (8 chunks), wave does 4 Mtiles x 4 gate-tiles
    f32x4 acc[4][4] = {};
    #pragma unroll
    for (int kc = 0; kc < 8; ++kc) {
      bf16x8 af[4];
      #pragma unroll
      for (int mt = 0; mt < 4; ++mt) {
        int r = mt*16 + lr, k = kc*32 + lg*8;
        af[mt] = *(bf16x8*)((char*)u + (((r << 9) + (k << 1)) ^ ((r & 7) << 4)));
      }
      #pragma unroll
      for (int g = 0; g < 4; ++g) {
        int n = g*128 + jw + lr;
        bf16x8 bfr = *(const bf16x8*)(Wc + n*256 + kc*32 + lg*8);
        #pragma unroll
        for (int mt = 0; mt < 4; ++mt)
          acc[mt][g] = __builtin_amdgcn_mfma_f32_16x16x32_bf16(af[mt], bfr, acc[mt][g], 0, 0, 0);
      }
    }
    __syncthreads();   // all gate/emit LDS reads done before h overwrite

    #pragma unroll
    for (int mt = 0; mt < 4; ++mt) {
      #pragma unroll
      for (int reg = 0; reg < 4; ++reg) {
        float gi = sigm(acc[mt][0][reg] + bi);
        float gf = sigm(acc[mt][1][reg] + bff);
        float gg = tanhc(acc[mt][2][reg] + bg);
        float go = sigm(acc[mt][3][reg] + bo);
        float cc = gf * c[mt][reg] + gi * gg;
        c[mt][reg] = cc;
        float h = go * tanhc(cc);
        int rr = mt*16 + lg*4 + reg;
        int k = 128 + j;
        *(short*)((char*)u + (((rr << 9) + (k << 1)) ^ ((rr & 7) << 4))) = f2bf(h);
      }
    }
    // next iteration's top __syncthreads orders these h writes before their reads
  }
}

// Finish: alpha via MFMA, x_c, masked-L1 loss partials. One block = 64 (b,t) pairs.
__global__ __launch_bounds__(256) void finish_kernel(
  const float* __restrict__ fv, const float* __restrict__ fm, const float* __restrict__ fd,
  const float* __restrict__ bwc, const float* __restrict__ bhist,
  const char* __restrict__ ws, float* __restrict__ out)
{
  const short* Wp = (const short*)(ws + WS_WP);
  float* lacc = (float*)(ws + WS_LACC);
  float* imp = out + 1;
  __shared__ short u2[64*128];
  __shared__ float nloc[36], dloc[36];
  int tid = threadIdx.x, w = tid >> 6, l = tid & 63;
  int lr = l & 15, lg = l >> 4;
  int p0 = blockIdx.x * 64;

  if (tid < 36) { nloc[tid] = 0.f; dloc[tid] = 0.f; }

  // u2 row = (b,t) pair: k 0..35 = m, 36..71 = d, 72..127 = 0. Swizzled, row stride 256B.
  for (int idx = tid; idx < 2048; idx += 256) {
    int r = idx >> 5, q = idx & 31;
    int p = p0 + r;
    short4 s4 = {0,0,0,0};
    if (q < 9) {
      float4 x4 = *(const float4*)(fm + p*36 + q*4);
      s4 = make_short4(f2bf(x4.x), f2bf(x4.y), f2bf(x4.z), f2bf(x4.w));
    } else if (q < 18) {
      float4 x4 = *(const float4*)(fd + p*36 + (q - 9)*4);
      s4 = make_short4(f2bf(x4.x), f2bf(x4.y), f2bf(x4.z), f2bf(x4.w));
    }
    int k = q*4;
    int off = ((r << 8) + (k << 1)) ^ ((r & 7) << 4);
    *(short4*)((char*)u2 + off) = s4;
  }
  __syncthreads();

  f32x4 acc[3] = {};
  #pragma unroll
  for (int kc = 0; kc < 3; ++kc) {
    int r = w*16 + lr, k = kc*32 + lg*8;
    bf16x8 af = *(bf16x8*)((char*)u2 + (((r << 8) + (k << 1)) ^ ((r & 7) << 4)));
    #pragma unroll
    for (int nt = 0; nt < 3; ++nt) {
      int f = nt*16 + lr;
      bf16x8 bfr = *(const bf16x8*)(Wp + f*128 + kc*32 + lg*8);
      acc[nt] = __builtin_amdgcn_mfma_f32_16x16x32_bf16(af, bfr, acc[nt], 0, 0, 0);
    }
  }

  #pragma unroll
  for (int reg = 0; reg < 4; ++reg) {
    int rr = w*16 + lg*4 + reg;
    int p = p0 + rr;
    float ns = 0.f, ds = 0.f;
    #pragma unroll
    for (int nt = 0; nt < 3; ++nt) {
      int f = nt*16 + lr;
      if (f < 36) {
        int gi = p*36 + f;
        float alpha = sigm(acc[nt][reg] + bwc[f]);
        float xh = imp[gi] + bhist[f];
        float xc = alpha*xh + 1.f - alpha;
        imp[gi] = xc;
        float mm = fm[gi];
        ns += fabsf(fv[gi] - xc) * mm;
        ds += mm;
      }
    }
    #pragma unroll
    for (int s = 1; s < 16; s <<= 1) { ns += __shfl_xor(ns, s); ds += __shfl_xor(ds, s); }
    if (lr == 0) {
      int t = p % 36;
      atomicAdd(&nloc[t], ns);
      atomicAdd(&dloc[t], ds);
    }
  }
  __syncthreads();
  if (tid < 36) {
    atomicAdd(lacc + tid*16, nloc[tid]);
    atomicAdd(lacc + (36 + tid)*16, dloc[tid]);
  }
}

__global__ void loss_final_kernel(const char* __restrict__ ws, float* __restrict__ out){
  const float* lacc = (const float*)(ws + WS_LACC);
  int t = threadIdx.x;
  float v = 0.f;
  if (t < 36) v = lacc[t*16] / (lacc[(36 + t)*16] + 1e-5f);
  #pragma unroll
  for (int s = 1; s < 64; s <<= 1) v += __shfl_xor(v, s);
  if (t == 0) out[0] = 0.3f * v;
}

extern "C" void kernel_launch(void* const* d_in, const int* in_sizes, int n_in,
                              void* d_out, int out_size, void* d_ws, size_t ws_size,
                              hipStream_t stream)
{
  const float* fv    = (const float*)d_in[0];
  const float* fm    = (const float*)d_in[1];
  const float* fd    = (const float*)d_in[2];
  const float* fe    = (const float*)d_in[3];
  const float* fem   = (const float*)d_in[4];
  const float* bv    = (const float*)d_in[5];
  const float* bm    = (const float*)d_in[6];
  const float* bd    = (const float*)d_in[7];
  const float* Wih   = (const float*)d_in[8];
  const float* Whh   = (const float*)d_in[9];
  const float* bih   = (const float*)d_in[10];
  const float* bhh   = (const float*)d_in[11];
  const float* Whist = (const float*)d_in[12];
  const float* bhist = (const float*)d_in[13];
  const float* Wwc   = (const float*)d_in[14];
  const float* bwc   = (const float*)d_in[15];
  float* out = (float*)d_out;
  char* ws = (char*)d_ws;

  hipMemsetAsync(out + 1, 0, (size_t)N_ELEM*4, stream);
  prep_kernel<<<512, 256, 0, stream>>>(Wih, Whh, bih, bhh, Whist, Wwc, ws);
  lstm_kernel<<<256, 512, 0, stream>>>(fv, fm, fd, bv, bm, bd, ws, out);
  finish_kernel<<<4608, 256, 0, stream>>>(fv, fm, fd, bwc, bhist, ws, out);
  loss_final_kernel<<<1, 64, 0, stream>>>(ws, out);

  hipMemcpyAsync(out + 1 + (size_t)N_ELEM, fe,  (size_t)N_ELEM*4, hipMemcpyDeviceToDevice, stream);
  hipMemcpyAsync(out + 1 + 2*(size_t)N_ELEM, fem, (size_t)N_ELEM*4, hipMemcpyDeviceToDevice, stream);
}

// Round 2
// 908.595 us; speedup vs baseline: 1.1737x; 1.1737x over previous
//
#include <hip/hip_runtime.h>

#define B_ 8192
#define T_ 36
#define F_ 36
#define N_ELEM (B_*T_*F_)   // 10616832

typedef __attribute__((ext_vector_type(8))) short bf16x8;
typedef __attribute__((ext_vector_type(4))) float f32x4;

__device__ inline short f2bf(float x){
  union { float f; unsigned u; } v; v.f = x;
  unsigned r = v.u + 0x7FFFu + ((v.u >> 16) & 1u);
  return (short)(r >> 16);
}
__device__ inline float sigm(float x){ return 1.f/(1.f+__expf(-x)); }
__device__ inline float tanhc(float x){
  x = fminf(fmaxf(x, -15.f), 15.f);
  float e = __expf(-2.f*x);
  return (1.f - e)/(1.f + e);
}

// ws layout (bytes)
#define WS_WC   0         // bf16 [512][256]: cols 0..107=W_ih, 108..127=0, 128..255=W_hh
#define WS_WH   262144    // bf16 [2][64][128]: W_hist per direction, rows 36..63 = 0
#define WS_WP   294912    // bf16 [48][128]:   W_wc padded (k 72..127 = 0)
#define WS_BIAS 307200    // f32 [512]: b_ih + b_hh
#define WS_LACC 309248    // f32 [72][16]: num[t] at [t][0], den[t] at [36+t][0]

__global__ __launch_bounds__(256) void prep_kernel(
    const float* __restrict__ Wih, const float* __restrict__ Whh,
    const float* __restrict__ bih, const float* __restrict__ bhh,
    const float* __restrict__ Whist, const float* __restrict__ Wwc,
    char* __restrict__ ws)
{
  short* Wc   = (short*)(ws + WS_WC);
  short* Wh   = (short*)(ws + WS_WH);
  short* Wp   = (short*)(ws + WS_WP);
  float* bias = (float*)(ws + WS_BIAS);
  float* lacc = (float*)(ws + WS_LACC);
  int i = blockIdx.x*256 + threadIdx.x;
  if (i < 131072){
    int n = i >> 8, k = i & 255;
    float v = 0.f;
    if (k < 108) v = Wih[n*108 + k];
    else if (k >= 128) v = Whh[n*128 + (k - 128)];
    Wc[i] = f2bf(v);
  }
  if (i < 16384){
    int d = i >> 13, f = (i >> 7) & 63, k = i & 127;
    Wh[i] = (f < 36) ? f2bf(Whist[f*256 + d*128 + k]) : (short)0;
  }
  if (i < 6144){
    int f = i >> 7, k = i & 127;
    Wp[i] = (f < 36 && k < 72) ? f2bf(Wwc[f*72 + k]) : (short)0;
  }
  if (i < 512) bias[i] = bih[i] + bhh[i];
  if (i < 1152) lacc[i] = 0.f;
}

// Persistent LSTM: one block = 32 batch rows x one direction, 8 waves, 2 blocks/CU.
// LDS: xb[2][32][128] bf16 (k 0..107 = x_t), hb[2][32][128] bf16. XOR swizzle byte^=(row&7)<<4.
// One barrier per step (double-buffered x and h). Next-t x prefetched into regs at step top.
// Emit: xh[dir] = h_t @ W_hist_dir^T stored f32 to out regions (no atomics, no memset).
__global__ __launch_bounds__(512, 4) void lstm_kernel(
  const float* __restrict__ fv, const float* __restrict__ fm, const float* __restrict__ fd,
  const float* __restrict__ bv, const float* __restrict__ bm, const float* __restrict__ bd,
  const char* __restrict__ ws, float* __restrict__ out)
{
  int dir = blockIdx.x & 1, tile = blockIdx.x >> 1;
  int b0 = tile * 32;
  const float* V = dir ? bv : fv;
  const float* M = dir ? bm : fm;
  const float* D = dir ? bd : fd;
  const short* Wc   = (const short*)(ws + WS_WC);
  const short* Wh   = (const short*)(ws + WS_WH) + dir*8192;
  const float* bias = (const float*)(ws + WS_BIAS);
  float* xh = out + 1 + (size_t)dir * N_ELEM;   // dir0 -> imp region, dir1 -> fe region (scratch)

  __shared__ short xb[2][4096];
  __shared__ short hb[2][4096];
  int tid = threadIdx.x, w = tid >> 6, l = tid & 63;
  int lr = l & 15, lg = l >> 4;
  int jw = w * 16, j = jw + lr;
  int emt = w & 1, ent = w >> 1;      // emit tile (M-tile, F-tile); ent==3 idle

  // zero LDS (hb[0] must be zero = h_0; xb pad cols must be zero)
  {
    int* z1 = (int*)xb; int* z2 = (int*)hb;
    for (int i = tid; i < 4096; i += 512) { z1[i] = 0; z2[i] = 0; }
  }

  // per-thread staging items (t-invariant mapping): 864 float4 items = 3 arrays x 32 rows x 9
  int i0 = tid;
  int a0 = i0 / 288, r0 = (i0 % 288) / 9, q0 = i0 % 9;
  const float* p0 = (a0 == 0 ? V : (a0 == 1 ? M : D)) + (size_t)(b0 + r0)*1296 + q0*4;
  int o0 = (((r0 << 8) + ((a0*36 + q0*4) << 1)) ^ ((r0 & 7) << 4));
  bool has1 = tid < 352;
  int i1 = tid + 512;
  int a1 = i1 / 288, r1 = (i1 % 288) / 9, q1 = i1 % 9;
  const float* p1 = (a1 == 0 ? V : (a1 == 1 ? M : D)) + (size_t)(b0 + r1)*1296 + q1*4;
  int o1 = (((r1 << 8) + ((a1*36 + q1*4) << 1)) ^ ((r1 & 7) << 4));

  float c[2][4];
  #pragma unroll
  for (int a = 0; a < 2; ++a)
    #pragma unroll
    for (int b = 0; b < 4; ++b) c[a][b] = 0.f;

  float bi = bias[j], bff = bias[128 + j], bg = bias[256 + j], bo = bias[384 + j];

  // prologue: stage t=0 into xb[0]
  {
    float4 f0 = *(const float4*)p0;
    short4 s0 = { f2bf(f0.x), f2bf(f0.y), f2bf(f0.z), f2bf(f0.w) };
    *(short4*)((char*)xb[0] + o0) = s0;
    if (has1) {
      float4 f1 = *(const float4*)p1;
      short4 s1 = { f2bf(f1.x), f2bf(f1.y), f2bf(f1.z), f2bf(f1.w) };
      *(short4*)((char*)xb[0] + o1) = s1;
    }
  }
  __syncthreads();

  int cur = 0;
  for (int t = 0; t < 36; ++t) {
    int nxt = cur ^ 1;
    bool pre = t < 35;
    // T14: issue next-step global loads early; LDS write deferred to end of step
    float4 f0, f1;
    if (pre) {
      f0 = *(const float4*)(p0 + (t + 1)*36);
      if (has1) f1 = *(const float4*)(p1 + (t + 1)*36);
    }

    // emit pre-update hidden: xh = h_t @ W_hist_dir^T (plain stores)
    if (ent < 3) {
      int tout = dir ? (35 - t) : t;
      f32x4 ea = {0.f, 0.f, 0.f, 0.f};
      #pragma unroll
      for (int kc = 0; kc < 4; ++kc) {
        int r = emt*16 + lr, k = kc*32 + lg*8;
        bf16x8 af = *(bf16x8*)((char*)hb[cur] + (((r << 8) + (k << 1)) ^ ((r & 7) << 4)));
        bf16x8 bfr = *(const bf16x8*)(Wh + (ent*16 + lr)*128 + kc*32 + lg*8);
        ea = __builtin_amdgcn_mfma_f32_16x16x32_bf16(af, bfr, ea, 0, 0, 0);
      }
      int f = ent*16 + lr;
      if (f < 36) {
        #pragma unroll
        for (int reg = 0; reg < 4; ++reg) {
          int rr = emt*16 + lg*4 + reg;
          xh[((size_t)(b0 + rr)*36 + tout)*36 + f] = ea[reg];
        }
      }
    }

    if (t == 35) break;

    // gates = [x_t | h_t] @ Wc^T : kc 0..3 from xb, kc 4..7 from hb
    f32x4 acc[2][4] = {};
    #pragma unroll
    for (int kc = 0; kc < 8; ++kc) {
      const short* ub = (kc < 4) ? xb[cur] : hb[cur];
      int kk = (kc & 3)*32 + lg*8;
      bf16x8 af[2];
      #pragma unroll
      for (int mt = 0; mt < 2; ++mt) {
        int r = mt*16 + lr;
        af[mt] = *(bf16x8*)((char*)ub + (((r << 8) + (kk << 1)) ^ ((r & 7) << 4)));
      }
      #pragma unroll
      for (int g = 0; g < 4; ++g) {
        bf16x8 bfr = *(const bf16x8*)(Wc + (size_t)(g*128 + j)*256 + kc*32 + lg*8);
        #pragma unroll
        for (int mt = 0; mt < 2; ++mt)
          acc[mt][g] = __builtin_amdgcn_mfma_f32_16x16x32_bf16(af[mt], bfr, acc[mt][g], 0, 0, 0);
      }
    }

    // elementwise -> h_{t+1} into hb[nxt]
    #pragma unroll
    for (int mt = 0; mt < 2; ++mt) {
      #pragma unroll
      for (int reg = 0; reg < 4; ++reg) {
        float gi = sigm(acc[mt][0][reg] + bi);
        float gf = sigm(acc[mt][1][reg] + bff);
        float gg = tanhc(acc[mt][2][reg] + bg);
        float go = sigm(acc[mt][3][reg] + bo);
        float cc = gf * c[mt][reg] + gi * gg;
        c[mt][reg] = cc;
        float h = go * tanhc(cc);
        int rr = mt*16 + lg*4 + reg;
        *(short*)((char*)hb[nxt] + (((rr << 8) + (j << 1)) ^ ((rr & 7) << 4))) = f2bf(h);
      }
    }

    // write prefetched x_{t+1} into xb[nxt]
    {
      short4 s0 = { f2bf(f0.x), f2bf(f0.y), f2bf(f0.z), f2bf(f0.w) };
      *(short4*)((char*)xb[nxt] + o0) = s0;
      if (has1) {
        short4 s1 = { f2bf(f1.x), f2bf(f1.y), f2bf(f1.z), f2bf(f1.w) };
        *(short4*)((char*)xb[nxt] + o1) = s1;
      }
    }

    __syncthreads();
    cur = nxt;
  }
}

// Finish: alpha via MFMA, x_c = alpha*(xh_f+xh_b+b_hist)+1-alpha, masked-L1 partials.
__global__ __launch_bounds__(256) void finish_kernel(
  const float* __restrict__ fv, const float* __restrict__ fm, const float* __restrict__ fd,
  const float* __restrict__ bwc, const float* __restrict__ bhist,
  const char* __restrict__ ws, float* __restrict__ out)
{
  const short* Wp = (const short*)(ws + WS_WP);
  float* lacc = (float*)(ws + WS_LACC);
  float* imp = out + 1;                                  // also xh_f input
  const float* xhb = out + 1 + (size_t)N_ELEM;           // xh_b input (scratch region)
  __shared__ short u2[64*128];
  __shared__ float nloc[36], dloc[36];
  int tid = threadIdx.x, w = tid >> 6, l = tid & 63;
  int lr = l & 15, lg = l >> 4;
  int p0 = blockIdx.x * 64;

  if (tid < 36) { nloc[tid] = 0.f; dloc[tid] = 0.f; }

  // u2 row = (b,t) pair: k 0..35 = m, 36..71 = d, 72..127 = 0. Swizzled, row stride 256B.
  for (int idx = tid; idx < 2048; idx += 256) {
    int r = idx >> 5, q = idx & 31;
    int p = p0 + r;
    short4 s4 = {0,0,0,0};
    if (q < 9) {
      float4 x4 = *(const float4*)(fm + (size_t)p*36 + q*4);
      s4 = make_short4(f2bf(x4.x), f2bf(x4.y), f2bf(x4.z), f2bf(x4.w));
    } else if (q < 18) {
      float4 x4 = *(const float4*)(fd + (size_t)p*36 + (q - 9)*4);
      s4 = make_short4(f2bf(x4.x), f2bf(x4.y), f2bf(x4.z), f2bf(x4.w));
    }
    int k = q*4;
    int off = ((r << 8) + (k << 1)) ^ ((r & 7) << 4);
    *(short4*)((char*)u2 + off) = s4;
  }
  __syncthreads();

  f32x4 acc[3] = {};
  #pragma unroll
  for (int kc = 0; kc < 3; ++kc) {
    int r = w*16 + lr, k = kc*32 + lg*8;
    bf16x8 af = *(bf16x8*)((char*)u2 + (((r << 8) + (k << 1)) ^ ((r & 7) << 4)));
    #pragma unroll
    for (int nt = 0; nt < 3; ++nt) {
      int f = nt*16 + lr;
      bf16x8 bfr = *(const bf16x8*)(Wp + f*128 + kc*32 + lg*8);
      acc[nt] = __builtin_amdgcn_mfma_f32_16x16x32_bf16(af, bfr, acc[nt], 0, 0, 0);
    }
  }

  #pragma unroll
  for (int reg = 0; reg < 4; ++reg) {
    int rr = w*16 + lg*4 + reg;
    int p = p0 + rr;
    float ns = 0.f, ds = 0.f;
    #pragma unroll
    for (int nt = 0; nt < 3; ++nt) {
      int f = nt*16 + lr;
      if (f < 36) {
        size_t gi = (size_t)p*36 + f;
        float alpha = sigm(acc[nt][reg] + bwc[f]);
        float xhv = imp[gi] + xhb[gi] + bhist[f];
        float xc = alpha*xhv + 1.f - alpha;
        imp[gi] = xc;
        float mm = fm[gi];
        ns += fabsf(fv[gi] - xc) * mm;
        ds += mm;
      }
    }
    #pragma unroll
    for (int s = 1; s < 16; s <<= 1) { ns += __shfl_xor(ns, s); ds += __shfl_xor(ds, s); }
    if (lr == 0) {
      int t = p % 36;
      atomicAdd(&nloc[t], ns);
      atomicAdd(&dloc[t], ds);
    }
  }
  __syncthreads();
  if (tid < 36) {
    atomicAdd(lacc + tid*16, nloc[tid]);
    atomicAdd(lacc + (36 + tid)*16, dloc[tid]);
  }
}

__global__ void loss_final_kernel(const char* __restrict__ ws, float* __restrict__ out){
  const float* lacc = (const float*)(ws + WS_LACC);
  int t = threadIdx.x;
  float v = 0.f;
  if (t < 36) v = lacc[t*16] / (lacc[(36 + t)*16] + 1e-5f);
  #pragma unroll
  for (int s = 1; s < 64; s <<= 1) v += __shfl_xor(v, s);
  if (t == 0) out[0] = 0.3f * v;
}

extern "C" void kernel_launch(void* const* d_in, const int* in_sizes, int n_in,
                              void* d_out, int out_size, void* d_ws, size_t ws_size,
                              hipStream_t stream)
{
  const float* fv    = (const float*)d_in[0];
  const float* fm    = (const float*)d_in[1];
  const float* fd    = (const float*)d_in[2];
  const float* fe    = (const float*)d_in[3];
  const float* fem   = (const float*)d_in[4];
  const float* bv    = (const float*)d_in[5];
  const float* bm    = (const float*)d_in[6];
  const float* bd    = (const float*)d_in[7];
  const float* Wih   = (const float*)d_in[8];
  const float* Whh   = (const float*)d_in[9];
  const float* bih   = (const float*)d_in[10];
  const float* bhh   = (const float*)d_in[11];
  const float* Whist = (const float*)d_in[12];
  const float* bhist = (const float*)d_in[13];
  const float* Wwc   = (const float*)d_in[14];
  const float* bwc   = (const float*)d_in[15];
  float* out = (float*)d_out;
  char* ws = (char*)d_ws;

  prep_kernel<<<512, 256, 0, stream>>>(Wih, Whh, bih, bhh, Whist, Wwc, ws);
  lstm_kernel<<<512, 512, 0, stream>>>(fv, fm, fd, bv, bm, bd, ws, out);
  finish_kernel<<<4608, 256, 0, stream>>>(fv, fm, fd, bwc, bhist, ws, out);
  loss_final_kernel<<<1, 64, 0, stream>>>(ws, out);

  hipMemcpyAsync(out + 1 + (size_t)N_ELEM, fe,  (size_t)N_ELEM*4, hipMemcpyDeviceToDevice, stream);
  hipMemcpyAsync(out + 1 + 2*(size_t)N_ELEM, fem, (size_t)N_ELEM*4, hipMemcpyDeviceToDevice, stream);
}

// Round 3
// 646.697 us; speedup vs baseline: 1.6490x; 1.4050x over previous
//
#include <hip/hip_runtime.h>

#define B_ 8192
#define T_ 36
#define F_ 36
#define N_ELEM (B_*T_*F_)   // 10616832

typedef __attribute__((ext_vector_type(8))) short bf16x8;
typedef __attribute__((ext_vector_type(4))) float f32x4;

__device__ inline short f2bf(float x){
  union { float f; unsigned u; } v; v.f = x;
  unsigned r = v.u + 0x7FFFu + ((v.u >> 16) & 1u);
  return (short)(r >> 16);
}
__device__ inline float sigm(float x){ return 1.f/(1.f+__expf(-x)); }
__device__ inline float tanhc(float x){
  x = fminf(fmaxf(x, -15.f), 15.f);
  float e = __expf(-2.f*x);
  return (1.f - e)/(1.f + e);
}

// ws layout (bytes)
#define WS_WC   0         // bf16 [512][256]: cols 0..107=W_ih, 108..127=0, 128..255=W_hh
#define WS_WH   262144    // bf16 [2][64][128]: W_hist per direction, rows 36..63 = 0
#define WS_WP   294912    // bf16 [48][128]:   W_wc padded (k 72..127 = 0)
#define WS_BIAS 307200    // f32 [512]: b_ih + b_hh
#define WS_LACC 309248    // f32 [72][16]: num[t] at [t][0], den[t] at [36+t][0]

__global__ __launch_bounds__(256) void prep_kernel(
    const float* __restrict__ Wih, const float* __restrict__ Whh,
    const float* __restrict__ bih, const float* __restrict__ bhh,
    const float* __restrict__ Whist, const float* __restrict__ Wwc,
    char* __restrict__ ws)
{
  short* Wc   = (short*)(ws + WS_WC);
  short* Wh   = (short*)(ws + WS_WH);
  short* Wp   = (short*)(ws + WS_WP);
  float* bias = (float*)(ws + WS_BIAS);
  float* lacc = (float*)(ws + WS_LACC);
  int i = blockIdx.x*256 + threadIdx.x;
  if (i < 131072){
    int n = i >> 8, k = i & 255;
    float v = 0.f;
    if (k < 108) v = Wih[n*108 + k];
    else if (k >= 128) v = Whh[n*128 + (k - 128)];
    Wc[i] = f2bf(v);
  }
  if (i < 16384){
    int d = i >> 13, f = (i >> 7) & 63, k = i & 127;
    Wh[i] = (f < 36) ? f2bf(Whist[f*256 + d*128 + k]) : (short)0;
  }
  if (i < 6144){
    int f = i >> 7, k = i & 127;
    Wp[i] = (f < 36 && k < 72) ? f2bf(Wwc[f*72 + k]) : (short)0;
  }
  if (i < 512) bias[i] = bih[i] + bhh[i];
  if (i < 1152) lacc[i] = 0.f;
}

// Persistent LSTM: one block = 32 batch rows x one direction, 8 waves, 1 block/CU (2 rounds).
// Gate weights live in REGISTERS (wave w owns gate cols w*16..w*16+15 of all 4 gates = 128 VGPR).
// Inputs staged in 4-step chunks regs->LDS (sequential HBM reads). xh written via LDS slice
// as contiguous [t][b][f] nontemporal stores. One barrier/step (+1 per chunk boundary).
__global__ __launch_bounds__(512, 2) void lstm_kernel(
  const float* __restrict__ fv, const float* __restrict__ fm, const float* __restrict__ fd,
  const float* __restrict__ bv, const float* __restrict__ bm, const float* __restrict__ bd,
  const char* __restrict__ ws, float* __restrict__ out)
{
  int dir = blockIdx.x & 1, tile = blockIdx.x >> 1;
  int b0 = tile * 32;
  const float* V = dir ? bv : fv;
  const float* M = dir ? bm : fm;
  const float* D = dir ? bd : fd;
  const short* Wc   = (const short*)(ws + WS_WC);
  const short* Wh   = (const short*)(ws + WS_WH) + dir*8192;
  const float* bias = (const float*)(ws + WS_BIAS);
  float* xh = out + 1 + (size_t)(1 + dir) * N_ELEM;  // [t][b][f]; dir0 -> fe region, dir1 -> fem region

  __shared__ short xch[4][4096];     // 4 t-slices [32][128] bf16, swizzled
  __shared__ short hb[2][4096];      // h double buffer [32][128] bf16, swizzled
  __shared__ float xhs[2][1280];     // xh slice dbuf [32][40] f32

  int tid = threadIdx.x, w = tid >> 6, l = tid & 63;
  int lr = l & 15, lg = l >> 4;
  int j = w*16 + lr;
  int emt = w & 1, ent = w >> 1;     // emit M-tile / F-tile; ent==3 idle

  {
    int* z = (int*)hb;
    #pragma unroll
    for (int i = 0; i < 8; ++i) z[tid + i*512] = 0;
    int* zx = (int*)xch;
    #pragma unroll
    for (int i = 0; i < 16; ++i) zx[tid + i*512] = 0;
  }

  // gate weights -> registers (once)
  bf16x8 wreg[8][4];
  #pragma unroll
  for (int kc = 0; kc < 8; ++kc)
    #pragma unroll
    for (int g = 0; g < 4; ++g)
      wreg[kc][g] = *(const bf16x8*)(Wc + (g*128 + j)*256 + kc*32 + lg*8);
  bf16x8 whr[4];
  {
    int fr = (ent < 3 ? ent : 0)*16 + lr;
    #pragma unroll
    for (int kc = 0; kc < 4; ++kc)
      whr[kc] = *(const bf16x8*)(Wh + fr*128 + kc*32 + lg*8);
  }

  float c[2][4];
  #pragma unroll
  for (int a = 0; a < 2; ++a)
    #pragma unroll
    for (int b = 0; b < 4; ++b) c[a][b] = 0.f;
  float bi = bias[j], bff = bias[128 + j], bg = bias[256 + j], bo = bias[384 + j];

  f32x4 rg[7];
  auto load_chunk = [&](int ct) {
    #pragma unroll
    for (int k = 0; k < 7; ++k) {
      int i = tid + k*512;
      if (i < 3456) {
        int a = i / 1152, rem = i - a*1152;
        int r = rem / 36, q = rem - r*36;
        const float* src = (a == 0 ? V : (a == 1 ? M : D)) + (size_t)(b0 + r)*1296 + ct*36 + q*4;
        rg[k] = __builtin_nontemporal_load((const f32x4*)src);
      }
    }
  };
  auto write_chunk = [&]() {
    #pragma unroll
    for (int k = 0; k < 7; ++k) {
      int i = tid + k*512;
      if (i < 3456) {
        int a = i / 1152, rem = i - a*1152;
        int r = rem / 36, q = rem - r*36;
        int t_in = q / 9, fq = (q - t_in*9)*4;
        int kk = a*36 + fq;
        int off = ((r << 8) + (kk << 1)) ^ ((r & 7) << 4);
        short4 s = { f2bf(rg[k][0]), f2bf(rg[k][1]), f2bf(rg[k][2]), f2bf(rg[k][3]) };
        *(short4*)((char*)xch[t_in] + off) = s;
      }
    }
  };

  load_chunk(0);
  write_chunk();
  __syncthreads();

  int cur = 0;
  for (int t = 0; t < 36; ++t) {
    int s = t & 3;

    // coalesced store of previous step's xh slice (fire-and-forget, drains by next barrier)
    if (t > 0 && tid < 288) {
      int tprev = t - 1;
      int toutp = dir ? (35 - tprev) : tprev;
      int r = tid / 9, fq = (tid - r*9)*4;
      f32x4 v = *(const f32x4*)&xhs[tprev & 1][r*40 + fq];
      __builtin_nontemporal_store(v, (f32x4*)(xh + ((size_t)toutp*8192 + b0 + r)*36 + fq));
    }
    // prefetch next chunk into regs (consumed at next step's boundary)
    if (s == 2 && t < 32) load_chunk(t + 2);

    // emit xh_t = h_t @ W_hist^T into LDS slice
    if (ent < 3) {
      f32x4 ea = {0.f, 0.f, 0.f, 0.f};
      #pragma unroll
      for (int kc = 0; kc < 4; ++kc) {
        int r = emt*16 + lr, kk = kc*32 + lg*8;
        bf16x8 af = *(bf16x8*)((char*)hb[cur] + (((r << 8) + (kk << 1)) ^ ((r & 7) << 4)));
        ea = __builtin_amdgcn_mfma_f32_16x16x32_bf16(af, whr[kc], ea, 0, 0, 0);
      }
      int f = ent*16 + lr;
      if (f < 36) {
        #pragma unroll
        for (int reg = 0; reg < 4; ++reg)
          xhs[t & 1][(emt*16 + lg*4 + reg)*40 + f] = ea[reg];
      }
    }

    if (t < 35) {
      // gates = [x_t | h_t] @ Wc^T, weights from registers
      f32x4 acc[2][4] = {};
      #pragma unroll
      for (int kc = 0; kc < 8; ++kc) {
        const short* ub = (kc < 4) ? xch[s] : hb[cur];
        int kk = (kc & 3)*32 + lg*8;
        bf16x8 af[2];
        #pragma unroll
        for (int mt = 0; mt < 2; ++mt) {
          int r = mt*16 + lr;
          af[mt] = *(bf16x8*)((char*)ub + (((r << 8) + (kk << 1)) ^ ((r & 7) << 4)));
        }
        #pragma unroll
        for (int g = 0; g < 4; ++g)
          #pragma unroll
          for (int mt = 0; mt < 2; ++mt)
            acc[mt][g] = __builtin_amdgcn_mfma_f32_16x16x32_bf16(af[mt], wreg[kc][g], acc[mt][g], 0, 0, 0);
      }

      int nxt = cur ^ 1;
      #pragma unroll
      for (int mt = 0; mt < 2; ++mt) {
        #pragma unroll
        for (int reg = 0; reg < 4; ++reg) {
          float gi = sigm(acc[mt][0][reg] + bi);
          float gf = sigm(acc[mt][1][reg] + bff);
          float gg = tanhc(acc[mt][2][reg] + bg);
          float go = sigm(acc[mt][3][reg] + bo);
          float cc = gf * c[mt][reg] + gi * gg;
          c[mt][reg] = cc;
          float h = go * tanhc(cc);
          int rr = mt*16 + lg*4 + reg;
          *(short*)((char*)hb[nxt] + (((rr << 8) + (j << 1)) ^ ((rr & 7) << 4))) = f2bf(h);
        }
      }
      if (s == 3) { __syncthreads(); write_chunk(); }
      __syncthreads();
      cur = nxt;
    }
  }
  __syncthreads();
  if (tid < 288) {   // final slice t=35
    int toutp = dir ? 0 : 35;
    int r = tid / 9, fq = (tid - r*9)*4;
    f32x4 v = *(const f32x4*)&xhs[1][r*40 + fq];
    __builtin_nontemporal_store(v, (f32x4*)(xh + ((size_t)toutp*8192 + b0 + r)*36 + fq));
  }
}

// Finish (t-major): block = 64 consecutive b at one t. alpha via MFMA, x_c, masked-L1 partials.
__global__ __launch_bounds__(256) void finish_kernel(
  const float* __restrict__ fv, const float* __restrict__ fm, const float* __restrict__ fd,
  const float* __restrict__ bwc, const float* __restrict__ bhist,
  const char* __restrict__ ws, float* __restrict__ out)
{
  const short* Wp = (const short*)(ws + WS_WP);
  float* lacc = (float*)(ws + WS_LACC);
  float* imp = out + 1;
  const float* xhf = out + 1 + (size_t)N_ELEM;
  const float* xhb = out + 1 + 2*(size_t)N_ELEM;
  __shared__ short u2[8192];
  __shared__ float nacc, dacc;
  int tid = threadIdx.x, w = tid >> 6, l = tid & 63;
  int lr = l & 15, lg = l >> 4;
  int t = blockIdx.x >> 7;
  int b0 = (blockIdx.x & 127) * 64;

  if (tid == 0) { nacc = 0.f; dacc = 0.f; }

  // u2 row r = batch b0+r at fixed t: k 0..35 = m, 36..71 = d, 72..127 = 0. Swizzled.
  for (int idx = tid; idx < 2048; idx += 256) {
    int r = idx >> 5, q = idx & 31;
    short4 s4 = {0, 0, 0, 0};
    if (q < 9) {
      f32x4 x4 = *(const f32x4*)(fm + ((size_t)(b0 + r)*36 + t)*36 + q*4);
      s4 = make_short4(f2bf(x4[0]), f2bf(x4[1]), f2bf(x4[2]), f2bf(x4[3]));
    } else if (q < 18) {
      f32x4 x4 = *(const f32x4*)(fd + ((size_t)(b0 + r)*36 + t)*36 + (q - 9)*4);
      s4 = make_short4(f2bf(x4[0]), f2bf(x4[1]), f2bf(x4[2]), f2bf(x4[3]));
    }
    int off = ((r << 8) + ((q*4) << 1)) ^ ((r & 7) << 4);
    *(short4*)((char*)u2 + off) = s4;
  }
  __syncthreads();

  f32x4 acc[3] = {};
  #pragma unroll
  for (int kc = 0; kc < 3; ++kc) {
    int r = w*16 + lr, k = kc*32 + lg*8;
    bf16x8 af = *(bf16x8*)((char*)u2 + (((r << 8) + (k << 1)) ^ ((r & 7) << 4)));
    #pragma unroll
    for (int nt = 0; nt < 3; ++nt) {
      int f = nt*16 + lr;
      bf16x8 bfr = *(const bf16x8*)(Wp + f*128 + kc*32 + lg*8);
      acc[nt] = __builtin_amdgcn_mfma_f32_16x16x32_bf16(af, bfr, acc[nt], 0, 0, 0);
    }
  }

  #pragma unroll
  for (int reg = 0; reg < 4; ++reg) {
    int rr = w*16 + lg*4 + reg;
    size_t b = b0 + rr;
    float ns = 0.f, ds = 0.f;
    #pragma unroll
    for (int nt = 0; nt < 3; ++nt) {
      int f = nt*16 + lr;
      if (f < 36) {
        size_t gi  = (b*36 + t)*36 + f;
        size_t gi2 = ((size_t)t*8192 + b)*36 + f;
        float alpha = sigm(acc[nt][reg] + bwc[f]);
        float xhv = xhf[gi2] + xhb[gi2] + bhist[f];
        float xc = alpha*xhv + 1.f - alpha;
        imp[gi] = xc;
        float mm = fm[gi];
        ns += fabsf(fv[gi] - xc) * mm;
        ds += mm;
      }
    }
    #pragma unroll
    for (int s = 1; s < 16; s <<= 1) { ns += __shfl_xor(ns, s); ds += __shfl_xor(ds, s); }
    if (lr == 0) { atomicAdd(&nacc, ns); atomicAdd(&dacc, ds); }
  }
  __syncthreads();
  if (tid == 0) {
    atomicAdd(lacc + t*16, nacc);
    atomicAdd(lacc + (36 + t)*16, dacc);
  }
}

__global__ void loss_final_kernel(const char* __restrict__ ws, float* __restrict__ out){
  const float* lacc = (const float*)(ws + WS_LACC);
  int t = threadIdx.x;
  float v = 0.f;
  if (t < 36) v = lacc[t*16] / (lacc[(36 + t)*16] + 1e-5f);
  #pragma unroll
  for (int s = 1; s < 64; s <<= 1) v += __shfl_xor(v, s);
  if (t == 0) out[0] = 0.3f * v;
}

extern "C" void kernel_launch(void* const* d_in, const int* in_sizes, int n_in,
                              void* d_out, int out_size, void* d_ws, size_t ws_size,
                              hipStream_t stream)
{
  const float* fv    = (const float*)d_in[0];
  const float* fm    = (const float*)d_in[1];
  const float* fd    = (const float*)d_in[2];
  const float* fe    = (const float*)d_in[3];
  const float* fem   = (const float*)d_in[4];
  const float* bv    = (const float*)d_in[5];
  const float* bm    = (const float*)d_in[6];
  const float* bd    = (const float*)d_in[7];
  const float* Wih   = (const float*)d_in[8];
  const float* Whh   = (const float*)d_in[9];
  const float* bih   = (const float*)d_in[10];
  const float* bhh   = (const float*)d_in[11];
  const float* Whist = (const float*)d_in[12];
  const float* bhist = (const float*)d_in[13];
  const float* Wwc   = (const float*)d_in[14];
  const float* bwc   = (const float*)d_in[15];
  float* out = (float*)d_out;
  char* ws = (char*)d_ws;

  prep_kernel<<<512, 256, 0, stream>>>(Wih, Whh, bih, bhh, Whist, Wwc, ws);
  lstm_kernel<<<512, 512, 0, stream>>>(fv, fm, fd, bv, bm, bd, ws, out);
  finish_kernel<<<4608, 256, 0, stream>>>(fv, fm, fd, bwc, bhist, ws, out);
  loss_final_kernel<<<1, 64, 0, stream>>>(ws, out);

  hipMemcpyAsync(out + 1 + (size_t)N_ELEM, fe,  (size_t)N_ELEM*4, hipMemcpyDeviceToDevice, stream);
  hipMemcpyAsync(out + 1 + 2*(size_t)N_ELEM, fem, (size_t)N_ELEM*4, hipMemcpyDeviceToDevice, stream);
}

// Round 6
// 644.816 us; speedup vs baseline: 1.6538x; 1.0029x over previous
//
#include <hip/hip_runtime.h>

#define B_ 8192
#define T_ 36
#define F_ 36
#define N_ELEM (B_*T_*F_)   // 10616832
// bf16 xh scratch (ushort), 16B-aligned, inside fe/fem out regions
#define XHF_OFF (N_ELEM + 4)
#define XHB_OFF (2*N_ELEM + 4)

typedef __attribute__((ext_vector_type(8))) short bf16x8;
typedef __attribute__((ext_vector_type(4))) float f32x4;

__device__ inline short f2bf(float x){
  union { float f; unsigned u; } v; v.f = x;
  unsigned r = v.u + 0x7FFFu + ((v.u >> 16) & 1u);
  return (short)(r >> 16);
}
__device__ inline float bf2f(unsigned short u){
  union { unsigned u32; float f; } v; v.u32 = ((unsigned)u) << 16; return v.f;
}
__device__ inline float sigm(float x){ return 1.f/(1.f+__expf(-x)); }
__device__ inline float tanhc(float x){
  x = fminf(fmaxf(x, -15.f), 15.f);
  float e = __expf(-2.f*x);
  return (1.f - e)/(1.f + e);
}

// ws layout (bytes)
#define WS_WC   0         // bf16 [512][256]: cols 0..107=W_ih, 108..127=0, 128..255=W_hh
#define WS_WH   262144    // bf16 [2][64][128]: W_hist per direction, rows 36..63 = 0
#define WS_WP   294912    // bf16 [48][128]:   W_wc padded (k 72..127 = 0)
#define WS_BIAS 307200    // f32 [512]: b_ih + b_hh
#define WS_LACC 309248    // f32 [72][16]: num[t] at [t][0], den[t] at [36+t][0]

__global__ __launch_bounds__(256) void prep_kernel(
    const float* __restrict__ Wih, const float* __restrict__ Whh,
    const float* __restrict__ bih, const float* __restrict__ bhh,
    const float* __restrict__ Whist, const float* __restrict__ Wwc,
    char* __restrict__ ws)
{
  short* Wc   = (short*)(ws + WS_WC);
  short* Wh   = (short*)(ws + WS_WH);
  short* Wp   = (short*)(ws + WS_WP);
  float* bias = (float*)(ws + WS_BIAS);
  float* lacc = (float*)(ws + WS_LACC);
  int i = blockIdx.x*256 + threadIdx.x;
  if (i < 131072){
    int n = i >> 8, k = i & 255;
    float v = 0.f;
    if (k < 108) v = Wih[n*108 + k];
    else if (k >= 128) v = Whh[n*128 + (k - 128)];
    Wc[i] = f2bf(v);
  }
  if (i < 16384){
    int d = i >> 13, f = (i >> 7) & 63, k = i & 127;
    Wh[i] = (f < 36) ? f2bf(Whist[f*256 + d*128 + k]) : (short)0;
  }
  if (i < 6144){
    int f = i >> 7, k = i & 127;
    Wp[i] = (f < 36 && k < 72) ? f2bf(Wwc[f*72 + k]) : (short)0;
  }
  if (i < 512) bias[i] = bih[i] + bhh[i];
  if (i < 1152) lacc[i] = 0.f;
}

// Persistent LSTM: block = 32 rows x 1 dir, 8 waves, grid 512. Gate weights in
// registers. Inputs staged in 4-step chunks regs->LDS (sequential HBM reads).
// xh written via LDS slice as contiguous [t][b][f] bf16 stores (plain, not nt).
// Structure identical to the R3 PASS; only the xh store dtype/caching changed.
__global__ __launch_bounds__(512, 2) void lstm_kernel(
  const float* __restrict__ fv, const float* __restrict__ fm, const float* __restrict__ fd,
  const float* __restrict__ bv, const float* __restrict__ bm, const float* __restrict__ bd,
  const char* __restrict__ ws, float* __restrict__ out)
{
  int dir = blockIdx.x & 1, tile = blockIdx.x >> 1;
  int b0 = tile * 32;
  const float* V = dir ? bv : fv;
  const float* M = dir ? bm : fm;
  const float* D = dir ? bd : fd;
  const short* Wc   = (const short*)(ws + WS_WC);
  const short* Wh   = (const short*)(ws + WS_WH) + dir*8192;
  const float* bias = (const float*)(ws + WS_BIAS);
  unsigned short* xhg = (unsigned short*)(out + (dir ? XHB_OFF : XHF_OFF)); // [t][b][f] bf16

  __shared__ short xch[4][4096];     // 4 t-slices [32][128] bf16, swizzled
  __shared__ short hb[2][4096];      // h double buffer [32][128] bf16, swizzled
  __shared__ float xhs[2][1280];     // xh slice dbuf [32][40] f32

  int tid = threadIdx.x, w = tid >> 6, l = tid & 63;
  int lr = l & 15, lg = l >> 4;
  int j = w*16 + lr;
  int emt = w & 1, ent = w >> 1;     // emit M-tile / F-tile; ent==3 idle

  {
    int* z = (int*)hb;
    #pragma unroll
    for (int i = 0; i < 8; ++i) z[tid + i*512] = 0;
    int* zx = (int*)xch;
    #pragma unroll
    for (int i = 0; i < 16; ++i) zx[tid + i*512] = 0;
  }

  // gate weights -> registers (once)
  bf16x8 wreg[8][4];
  #pragma unroll
  for (int kc = 0; kc < 8; ++kc)
    #pragma unroll
    for (int g = 0; g < 4; ++g)
      wreg[kc][g] = *(const bf16x8*)(Wc + (g*128 + j)*256 + kc*32 + lg*8);
  bf16x8 whr[4];
  {
    int fr = (ent < 3 ? ent : 0)*16 + lr;
    #pragma unroll
    for (int kc = 0; kc < 4; ++kc)
      whr[kc] = *(const bf16x8*)(Wh + fr*128 + kc*32 + lg*8);
  }

  float c[2][4];
  #pragma unroll
  for (int a = 0; a < 2; ++a)
    #pragma unroll
    for (int b = 0; b < 4; ++b) c[a][b] = 0.f;
  float bi = bias[j], bff = bias[128 + j], bg = bias[256 + j], bo = bias[384 + j];

  f32x4 rg[7];
  auto load_chunk = [&](int ct) {
    #pragma unroll
    for (int k = 0; k < 7; ++k) {
      int i = tid + k*512;
      if (i < 3456) {
        int a = i / 1152, rem = i - a*1152;
        int r = rem / 36, q = rem - r*36;
        const float* src = (a == 0 ? V : (a == 1 ? M : D)) + (size_t)(b0 + r)*1296 + ct*36 + q*4;
        rg[k] = __builtin_nontemporal_load((const f32x4*)src);
      }
    }
  };
  auto write_chunk = [&]() {
    #pragma unroll
    for (int k = 0; k < 7; ++k) {
      int i = tid + k*512;
      if (i < 3456) {
        int a = i / 1152, rem = i - a*1152;
        int r = rem / 36, q = rem - r*36;
        int t_in = q / 9, fq = (q - t_in*9)*4;
        int kk = a*36 + fq;
        int off = ((r << 8) + (kk << 1)) ^ ((r & 7) << 4);
        short4 s = { f2bf(rg[k][0]), f2bf(rg[k][1]), f2bf(rg[k][2]), f2bf(rg[k][3]) };
        *(short4*)((char*)xch[t_in] + off) = s;
      }
    }
  };

  load_chunk(0);
  write_chunk();
  __syncthreads();

  int cur = 0;
  for (int t = 0; t < 36; ++t) {
    int s = t & 3;

    // store previous step's xh slice (bf16, plain stores; drains at this step's barrier)
    if (t > 0 && tid < 288) {
      int tprev = t - 1;
      int toutp = dir ? (35 - tprev) : tprev;
      int r = tid / 9, fq = (tid - r*9)*4;
      f32x4 v = *(const f32x4*)&xhs[tprev & 1][r*40 + fq];
      ushort4 sv = { (unsigned short)f2bf(v[0]), (unsigned short)f2bf(v[1]),
                     (unsigned short)f2bf(v[2]), (unsigned short)f2bf(v[3]) };
      *(ushort4*)(xhg + ((size_t)toutp*8192 + b0 + r)*36 + fq) = sv;
    }
    // prefetch next chunk into regs (consumed at next step's boundary)
    if (s == 2 && t < 32) load_chunk(t + 2);

    // emit xh_t = h_t @ W_hist^T into LDS slice
    if (ent < 3) {
      f32x4 ea = {0.f, 0.f, 0.f, 0.f};
      #pragma unroll
      for (int kc = 0; kc < 4; ++kc) {
        int r = emt*16 + lr, kk = kc*32 + lg*8;
        bf16x8 af = *(bf16x8*)((char*)hb[cur] + (((r << 8) + (kk << 1)) ^ ((r & 7) << 4)));
        ea = __builtin_amdgcn_mfma_f32_16x16x32_bf16(af, whr[kc], ea, 0, 0, 0);
      }
      int f = ent*16 + lr;
      if (f < 36) {
        #pragma unroll
        for (int reg = 0; reg < 4; ++reg)
          xhs[t & 1][(emt*16 + lg*4 + reg)*40 + f] = ea[reg];
      }
    }

    if (t < 35) {
      // gates = [x_t | h_t] @ Wc^T, weights from registers
      f32x4 acc[2][4] = {};
      #pragma unroll
      for (int kc = 0; kc < 8; ++kc) {
        const short* ub = (kc < 4) ? xch[s] : hb[cur];
        int kk = (kc & 3)*32 + lg*8;
        bf16x8 af[2];
        #pragma unroll
        for (int mt = 0; mt < 2; ++mt) {
          int r = mt*16 + lr;
          af[mt] = *(bf16x8*)((char*)ub + (((r << 8) + (kk << 1)) ^ ((r & 7) << 4)));
        }
        #pragma unroll
        for (int g = 0; g < 4; ++g)
          #pragma unroll
          for (int mt = 0; mt < 2; ++mt)
            acc[mt][g] = __builtin_amdgcn_mfma_f32_16x16x32_bf16(af[mt], wreg[kc][g], acc[mt][g], 0, 0, 0);
      }

      int nxt = cur ^ 1;
      #pragma unroll
      for (int mt = 0; mt < 2; ++mt) {
        #pragma unroll
        for (int reg = 0; reg < 4; ++reg) {
          float gi = sigm(acc[mt][0][reg] + bi);
          float gf = sigm(acc[mt][1][reg] + bff);
          float gg = tanhc(acc[mt][2][reg] + bg);
          float go = sigm(acc[mt][3][reg] + bo);
          float cc = gf * c[mt][reg] + gi * gg;
          c[mt][reg] = cc;
          float h = go * tanhc(cc);
          int rr = mt*16 + lg*4 + reg;
          *(short*)((char*)hb[nxt] + (((rr << 8) + (j << 1)) ^ ((rr & 7) << 4))) = f2bf(h);
        }
      }
      if (s == 3) { __syncthreads(); write_chunk(); }
      __syncthreads();
      cur = nxt;
    }
  }
  __syncthreads();
  if (tid < 288) {   // final slice t=35
    int toutp = dir ? 0 : 35;
    int r = tid / 9, fq = (tid - r*9)*4;
    f32x4 v = *(const f32x4*)&xhs[1][r*40 + fq];
    ushort4 sv = { (unsigned short)f2bf(v[0]), (unsigned short)f2bf(v[1]),
                   (unsigned short)f2bf(v[2]), (unsigned short)f2bf(v[3]) };
    *(ushort4*)(xhg + ((size_t)toutp*8192 + b0 + r)*36 + fq) = sv;
  }
}

// Finish (t-major): block = 64 consecutive b at one t. alpha via MFMA, x_c, masked-L1 partials.
__global__ __launch_bounds__(256) void finish_kernel(
  const float* __restrict__ fv, const float* __restrict__ fm, const float* __restrict__ fd,
  const float* __restrict__ bwc, const float* __restrict__ bhist,
  const char* __restrict__ ws, float* __restrict__ out)
{
  const short* Wp = (const short*)(ws + WS_WP);
  float* lacc = (float*)(ws + WS_LACC);
  float* imp = out + 1;
  const unsigned short* xhf = (const unsigned short*)(out + XHF_OFF);
  const unsigned short* xhb = (const unsigned short*)(out + XHB_OFF);
  __shared__ short u2[8192];
  __shared__ float nacc, dacc;
  int tid = threadIdx.x, w = tid >> 6, l = tid & 63;
  int lr = l & 15, lg = l >> 4;
  int t = blockIdx.x >> 7;
  int b0 = (blockIdx.x & 127) * 64;

  if (tid == 0) { nacc = 0.f; dacc = 0.f; }

  for (int idx = tid; idx < 2048; idx += 256) {
    int r = idx >> 5, q = idx & 31;
    short4 s4 = {0, 0, 0, 0};
    if (q < 9) {
      f32x4 x4 = *(const f32x4*)(fm + ((size_t)(b0 + r)*36 + t)*36 + q*4);
      s4 = make_short4(f2bf(x4[0]), f2bf(x4[1]), f2bf(x4[2]), f2bf(x4[3]));
    } else if (q < 18) {
      f32x4 x4 = *(const f32x4*)(fd + ((size_t)(b0 + r)*36 + t)*36 + (q - 9)*4);
      s4 = make_short4(f2bf(x4[0]), f2bf(x4[1]), f2bf(x4[2]), f2bf(x4[3]));
    }
    int off = ((r << 8) + ((q*4) << 1)) ^ ((r & 7) << 4);
    *(short4*)((char*)u2 + off) = s4;
  }
  __syncthreads();

  f32x4 acc[3] = {};
  #pragma unroll
  for (int kc = 0; kc < 3; ++kc) {
    int r = w*16 + lr, k = kc*32 + lg*8;
    bf16x8 af = *(bf16x8*)((char*)u2 + (((r << 8) + (k << 1)) ^ ((r & 7) << 4)));
    #pragma unroll
    for (int nt = 0; nt < 3; ++nt) {
      int f = nt*16 + lr;
      bf16x8 bfr = *(const bf16x8*)(Wp + f*128 + kc*32 + lg*8);
      acc[nt] = __builtin_amdgcn_mfma_f32_16x16x32_bf16(af, bfr, acc[nt], 0, 0, 0);
    }
  }

  #pragma unroll
  for (int reg = 0; reg < 4; ++reg) {
    int rr = w*16 + lg*4 + reg;
    size_t b = b0 + rr;
    float ns = 0.f, ds = 0.f;
    #pragma unroll
    for (int nt = 0; nt < 3; ++nt) {
      int f = nt*16 + lr;
      if (f < 36) {
        size_t gi  = (b*36 + t)*36 + f;
        size_t gi2 = ((size_t)t*8192 + b)*36 + f;
        float alpha = sigm(acc[nt][reg] + bwc[f]);
        float xhv = bf2f(xhf[gi2]) + bf2f(xhb[gi2]) + bhist[f];
        float xc = alpha*xhv + 1.f - alpha;
        imp[gi] = xc;
        float mm = fm[gi];
        ns += fabsf(fv[gi] - xc) * mm;
        ds += mm;
      }
    }
    #pragma unroll
    for (int s = 1; s < 16; s <<= 1) { ns += __shfl_xor(ns, s); ds += __shfl_xor(ds, s); }
    if (lr == 0) { atomicAdd(&nacc, ns); atomicAdd(&dacc, ds); }
  }
  __syncthreads();
  if (tid == 0) {
    atomicAdd(lacc + t*16, nacc);
    atomicAdd(lacc + (36 + t)*16, dacc);
  }
}

__global__ void loss_final_kernel(const char* __restrict__ ws, float* __restrict__ out){
  const float* lacc = (const float*)(ws + WS_LACC);
  int t = threadIdx.x;
  float v = 0.f;
  if (t < 36) v = lacc[t*16] / (lacc[(36 + t)*16] + 1e-5f);
  #pragma unroll
  for (int s = 1; s < 64; s <<= 1) v += __shfl_xor(v, s);
  if (t == 0) out[0] = 0.3f * v;
}

extern "C" void kernel_launch(void* const* d_in, const int* in_sizes, int n_in,
                              void* d_out, int out_size, void* d_ws, size_t ws_size,
                              hipStream_t stream)
{
  const float* fv    = (const float*)d_in[0];
  const float* fm    = (const float*)d_in[1];
  const float* fd    = (const float*)d_in[2];
  const float* fe    = (const float*)d_in[3];
  const float* fem   = (const float*)d_in[4];
  const float* bv    = (const float*)d_in[5];
  const float* bm    = (const float*)d_in[6];
  const float* bd    = (const float*)d_in[7];
  const float* Wih   = (const float*)d_in[8];
  const float* Whh   = (const float*)d_in[9];
  const float* bih   = (const float*)d_in[10];
  const float* bhh   = (const float*)d_in[11];
  const float* Whist = (const float*)d_in[12];
  const float* bhist = (const float*)d_in[13];
  const float* Wwc   = (const float*)d_in[14];
  const float* bwc   = (const float*)d_in[15];
  float* out = (float*)d_out;
  char* ws = (char*)d_ws;

  prep_kernel<<<512, 256, 0, stream>>>(Wih, Whh, bih, bhh, Whist, Wwc, ws);
  lstm_kernel<<<512, 512, 0, stream>>>(fv, fm, fd, bv, bm, bd, ws, out);
  finish_kernel<<<4608, 256, 0, stream>>>(fv, fm, fd, bwc, bhist, ws, out);
  loss_final_kernel<<<1, 64, 0, stream>>>(ws, out);

  hipMemcpyAsync(out + 1 + (size_t)N_ELEM, fe,  (size_t)N_ELEM*4, hipMemcpyDeviceToDevice, stream);
  hipMemcpyAsync(out + 1 + 2*(size_t)N_ELEM, fem, (size_t)N_ELEM*4, hipMemcpyDeviceToDevice, stream);
}